// Round 7
// baseline (2933.675 us; speedup 1.0000x reference)
//
#include <hip/hip_runtime.h>
#include <math.h>

typedef unsigned short ushort_t;
typedef unsigned int uint_t;

#define LRELU_SLOPE 0.2f

static __device__ __forceinline__ float bf2f(ushort_t h) {
    uint_t u = ((uint_t)h) << 16;
    return __builtin_bit_cast(float, u);
}

// f32-vs-packed-bf16 detector (r3/r4-calibrated: says f32 on this dataset,
// proven correct by the r2<->r3 NaN A/B).
static __device__ __forceinline__ int detect_isbf(const void* p) {
    const uint_t* w = (const uint_t*)p;
    int score = 0;
    for (int i = 0; i < 128; ++i) {
        uint_t e = ((w[i] & 0xFFFFu) >> 7) & 0xFFu;
        score += (e >= 90u && e <= 125u) ? 1 : 0;
    }
    return score >= 64;
}

static __device__ __forceinline__ float ldf(const void* p, size_t idx, int isbf) {
    return isbf ? bf2f(((const ushort_t*)p)[idx]) : ((const float*)p)[idx];
}

// ---------------------------------------------------------------------------
// K0: WT[k][o] = W[o][k] (f32), dims-general; publishes dtype flags.
// grid (D_IN, ceil(D_OUT/256)) x 256
// ---------------------------------------------------------------------------
__global__ void k0_prep(const void* __restrict__ hRaw, const void* __restrict__ WRaw,
                        const void* __restrict__ WbRaw, const void* __restrict__ awRaw,
                        float* __restrict__ WT, int* __restrict__ flags, int D_IN, int D_OUT) {
    const int isbfW = detect_isbf(WRaw);
    const int k = blockIdx.x;
    const int o = blockIdx.y * 256 + threadIdx.x;
    if (o < D_OUT) WT[(size_t)k * D_OUT + o] = ldf(WRaw, (size_t)o * D_IN + k, isbfW);
    if (blockIdx.x == 0 && blockIdx.y == 0 && threadIdx.x == 0) {
        flags[0] = detect_isbf(hRaw);
        flags[1] = isbfW;
        flags[2] = detect_isbf(WbRaw);
        flags[3] = detect_isbf(awRaw);
    }
}

// ---------------------------------------------------------------------------
// K1n: wh[i][o] = sum_k h[i][k]*WT[k][o] + Wb[o]   (f32 naive)
// grid (N, ceil(D_OUT/256)) x 256
// ---------------------------------------------------------------------------
__global__ void k1n(const void* __restrict__ hRaw, const float* __restrict__ WT,
                    const void* __restrict__ WbRaw, const int* __restrict__ flags,
                    float* __restrict__ wh, int D_IN, int D_OUT) {
    const int isbfH = flags[0], isbfB = flags[2];
    const int i = blockIdx.x;
    const int o = blockIdx.y * 256 + threadIdx.x;
    if (o >= D_OUT) return;
    float acc = 0.f;
    for (int k = 0; k < D_IN; ++k)
        acc += ldf(hRaw, (size_t)i * D_IN + k, isbfH) * WT[(size_t)k * D_OUT + o];
    wh[(size_t)i * D_OUT + o] = acc + ldf(WbRaw, o, isbfB);
}

// ---------------------------------------------------------------------------
// K1s: s_src[i], s_dst[i]. grid ceil(N/256) x 256, one thread per i.
// ---------------------------------------------------------------------------
__global__ void k1s(const float* __restrict__ wh, const void* __restrict__ awRaw,
                    const int* __restrict__ flags, float* __restrict__ ssrc,
                    float* __restrict__ sdst, int N, int D_OUT) {
    const int isbfA = flags[3];
    const int i = blockIdx.x * 256 + threadIdx.x;
    if (i >= N) return;
    float s1 = 0.f, s2 = 0.f;
    for (int o = 0; o < D_OUT; ++o) {
        const float v = wh[(size_t)i * D_OUT + o];
        s1 += v * ldf(awRaw, o, isbfA);
        s2 += v * ldf(awRaw, D_OUT + o, isbfA);
    }
    ssrc[i] = s1;
    sdst[i] = s2;
}

// ---------------------------------------------------------------------------
// K2n: naive fused masked-softmax + P@wh, f32 OUTPUT (the round-7 change).
// grid (N/8, ceil(D_OUT/256)) x 256; 8 rows/block, d = by*256+t.
// ---------------------------------------------------------------------------
__launch_bounds__(256)
__global__ void k2n(const int* __restrict__ adj, const float* __restrict__ wh,
                    const float* __restrict__ ssrcA, const float* __restrict__ sdstA,
                    const void* __restrict__ abRaw, const int* __restrict__ flags,
                    float* __restrict__ out, int N, int D_OUT) {
    __shared__ float pT[8][512];
    __shared__ float zr[8];

    const int t = threadIdx.x;
    const int i0 = blockIdx.x * 8;
    const int d = blockIdx.y * 256 + t;
    const float ab = flags[3] ? bf2f(((const ushort_t*)abRaw)[0]) : ((const float*)abRaw)[0];
    const int pr = t >> 5;
    const int jl = (t & 31) * 16;
    const float sr = ssrcA[i0 + pr];

    if (t < 8) zr[t] = 0.f;
    float zacc = 0.f;
    float acc[8];
#pragma unroll
    for (int r = 0; r < 8; ++r) acc[r] = 0.f;

    for (int jt = 0; jt < N; jt += 512) {
        __syncthreads();
        for (int u = 0; u < 16; ++u) {
            const int j = jt + jl + u;
            float pv = 0.f;
            if (j < N) {
                const int av = adj[(size_t)(i0 + pr) * N + j];
                float sc = sr + sdstA[j] + ab;
                sc = sc > 0.f ? sc : LRELU_SLOPE * sc;
                sc = fminf(sc, 60.f);
                pv = (av > 0) ? expf(sc) : 0.f;
            }
            pT[pr][jl + u] = pv;
            zacc += pv;
        }
        __syncthreads();
        if (d < D_OUT) {
            const int jmax = (N - jt < 512) ? (N - jt) : 512;
            for (int jj = 0; jj < jmax; ++jj) {
                const float whv = wh[(size_t)(jt + jj) * D_OUT + d];
#pragma unroll
                for (int r = 0; r < 8; ++r) acc[r] += pT[r][jj] * whv;
            }
        }
    }

    atomicAdd(&zr[pr], zacc);
    __syncthreads();
    if (d < D_OUT) {
#pragma unroll
        for (int r = 0; r < 8; ++r)
            out[(size_t)(i0 + r) * D_OUT + d] = acc[r] / fmaxf(zr[r], 1e-30f);
    }
}

extern "C" void kernel_launch(void* const* d_in, const int* in_sizes, int n_in, void* d_out,
                              int out_size, void* d_ws, size_t ws_size, hipStream_t stream) {
    // ---- identify inputs by size (kills order+dims assumptions) ----
    // expected: h=N*D_IN, adj=N*N, Ww=D_OUT*D_IN, Wb=D_OUT, aw=2*D_OUT, ab=1
    int idx_ab = 0, idx_adj = 0, idx_h = 0, idx_Ww = 0, idx_Wb = 0, idx_aw = 0;
    {
        long long sz[16];
        int order[16];
        for (int i = 0; i < n_in; ++i) { sz[i] = in_sizes[i]; order[i] = i; }
        // sort indices ascending by size (n_in == 6, tiny bubble sort)
        for (int a = 0; a < n_in; ++a)
            for (int b = a + 1; b < n_in; ++b)
                if (sz[order[b]] < sz[order[a]]) { int tmp = order[a]; order[a] = order[b]; order[b] = tmp; }
        idx_ab = order[0];   // 1
        idx_Wb = order[1];   // D_OUT
        idx_aw = order[2];   // 2*D_OUT
        idx_Ww = order[3];   // D_OUT*D_IN
        idx_h = order[4];    // N*D_IN
        idx_adj = order[5];  // N*N
    }
    const int D_OUT = in_sizes[idx_Wb];
    const int D_IN = in_sizes[idx_Ww] / D_OUT;
    const int N = in_sizes[idx_h] / D_IN;

    const void* h = d_in[idx_h];
    const int* adj = (const int*)d_in[idx_adj];
    const void* Ww = d_in[idx_Ww];
    const void* Wb = d_in[idx_Wb];
    const void* aw = d_in[idx_aw];
    const void* ab = d_in[idx_ab];

    char* ws = (char*)d_ws;
    int* flags = (int*)ws;                                  // 256 B
    float* WT = (float*)(ws + 256);                         // D_IN*D_OUT*4
    size_t off = 256 + (size_t)D_IN * D_OUT * 4;
    float* wh = (float*)(ws + off);                         // N*D_OUT*4
    off += (size_t)N * D_OUT * 4;
    float* ssrc = (float*)(ws + off);
    off += (size_t)N * 4;
    float* sdst = (float*)(ws + off);

    const int oChunks = (D_OUT + 255) / 256;
    hipLaunchKernelGGL(k0_prep, dim3(D_IN, oChunks), dim3(256), 0, stream, h, Ww, Wb, aw, WT,
                       flags, D_IN, D_OUT);
    hipLaunchKernelGGL(k1n, dim3(N, oChunks), dim3(256), 0, stream, h, WT, Wb, flags, wh, D_IN,
                       D_OUT);
    hipLaunchKernelGGL(k1s, dim3((N + 255) / 256), dim3(256), 0, stream, wh, aw, flags, ssrc,
                       sdst, N, D_OUT);
    hipLaunchKernelGGL(k2n, dim3(N / 8, oChunks), dim3(256), 0, stream, adj, wh, ssrc, sdst, ab,
                       flags, (float*)d_out, N, D_OUT);
}

// Round 8
// 485.242 us; speedup vs baseline: 6.0458x; 6.0458x over previous
//
#include <hip/hip_runtime.h>

typedef unsigned short ushort_t;
typedef unsigned int uint_t;
typedef __attribute__((ext_vector_type(8))) short short8;
typedef __attribute__((ext_vector_type(4))) float f32x4;
typedef __attribute__((ext_vector_type(4))) int i32x4;
typedef __attribute__((ext_vector_type(4))) uint_t u32x4;
typedef __attribute__((ext_vector_type(4))) ushort_t u16x4;

#define LRELU_SLOPE 0.2f

static __device__ __forceinline__ float bf2f(ushort_t h) {
    uint_t u = ((uint_t)h) << 16;
    return __builtin_bit_cast(float, u);
}
static __device__ __forceinline__ ushort_t f2bf(float f) {
    uint_t u = __builtin_bit_cast(uint_t, f);
    uint_t r = (u + 0x7fffu + ((u >> 16) & 1u)) >> 16;
    return (ushort_t)r;
}

// split 4 f32 into bf16 hi + bf16 residual (hi+lo ~ 16-bit mantissa accuracy)
static __device__ __forceinline__ void split4(float4 x, uint2& hi, uint2& lo) {
    ushort_t h0 = f2bf(x.x), h1 = f2bf(x.y), h2 = f2bf(x.z), h3 = f2bf(x.w);
    hi.x = (uint_t)h0 | ((uint_t)h1 << 16);
    hi.y = (uint_t)h2 | ((uint_t)h3 << 16);
    float r0 = x.x - bf2f(h0), r1 = x.y - bf2f(h1);
    float r2 = x.z - bf2f(h2), r3 = x.w - bf2f(h3);
    lo.x = (uint_t)f2bf(r0) | ((uint_t)f2bf(r1) << 16);
    lo.y = (uint_t)f2bf(r2) | ((uint_t)f2bf(r3) << 16);
}

// ---------------------------------------------------------------------------
// K1: whT[o][i] = sum_k W[o][k]*h[i][k] + Wb[o]  (bf16 whT, 256 x 8192)
//     + s_src/s_dst (f32, from f32 accumulators -> survives exp amplification)
// f32 inputs, split-staged hi/lo, 3 MFMAs per tile (hh + hl + lh).
// grid 256 x 256 (4 waves): block covers all 256 o, 32-wide i-tile.
// ---------------------------------------------------------------------------
__launch_bounds__(256, 2)
__global__ void k1_gemm(const float* __restrict__ h, const float* __restrict__ W,
                        const float* __restrict__ Wb, const float* __restrict__ aw,
                        ushort_t* __restrict__ whT, float* __restrict__ s_src,
                        float* __restrict__ s_dst) {
    __shared__ __align__(16) ushort_t aHi[256 * 40], aLo[256 * 40];  // W tile [o][k], k=32
    __shared__ __align__(16) ushort_t bHi[32 * 40], bLo[32 * 40];    // h tile [i][k]
    __shared__ float redLds[2][4][32];

    const int t = threadIdx.x;
    const int wv = t >> 6, ln = t & 63;
    const int i0 = blockIdx.x * 32;
    const int srow = t >> 3, sch = t & 7;  // 32 rows/round, 8 lanes/row, 4 f32/lane

    f32x4 acc[4][2];
#pragma unroll
    for (int mt = 0; mt < 4; ++mt)
#pragma unroll
        for (int nt = 0; nt < 2; ++nt) acc[mt][nt] = (f32x4){0.f, 0.f, 0.f, 0.f};

    for (int k0 = 0; k0 < 512; k0 += 32) {
        __syncthreads();
#pragma unroll
        for (int r = 0; r < 8; ++r) {
            float4 x = *(const float4*)(W + (size_t)(r * 32 + srow) * 512 + k0 + sch * 4);
            uint2 hi, lo;
            split4(x, hi, lo);
            *(uint2*)(aHi + (r * 32 + srow) * 40 + sch * 4) = hi;
            *(uint2*)(aLo + (r * 32 + srow) * 40 + sch * 4) = lo;
        }
        {
            float4 x = *(const float4*)(h + (size_t)(i0 + srow) * 512 + k0 + sch * 4);
            uint2 hi, lo;
            split4(x, hi, lo);
            *(uint2*)(bHi + srow * 40 + sch * 4) = hi;
            *(uint2*)(bLo + srow * 40 + sch * 4) = lo;
        }
        __syncthreads();
        {
            short8 bh[2], bl[2];
#pragma unroll
            for (int nt = 0; nt < 2; ++nt) {
                const int boff = (nt * 16 + (ln & 15)) * 40 + (ln >> 4) * 8;
                bh[nt] = *(const short8*)(bHi + boff);
                bl[nt] = *(const short8*)(bLo + boff);
            }
#pragma unroll
            for (int mt = 0; mt < 4; ++mt) {
                const int aoff = (wv * 64 + mt * 16 + (ln & 15)) * 40 + (ln >> 4) * 8;
                short8 ah = *(const short8*)(aHi + aoff);
                short8 al = *(const short8*)(aLo + aoff);
#pragma unroll
                for (int nt = 0; nt < 2; ++nt) {
                    acc[mt][nt] = __builtin_amdgcn_mfma_f32_16x16x32_bf16(ah, bh[nt], acc[mt][nt], 0, 0, 0);
                    acc[mt][nt] = __builtin_amdgcn_mfma_f32_16x16x32_bf16(ah, bl[nt], acc[mt][nt], 0, 0, 0);
                    acc[mt][nt] = __builtin_amdgcn_mfma_f32_16x16x32_bf16(al, bh[nt], acc[mt][nt], 0, 0, 0);
                }
            }
        }
    }

    // epilogue: bias, whT store (bf16), s partials (f32 exact accumulators)
    float psrc[2] = {0.f, 0.f}, pdst[2] = {0.f, 0.f};
#pragma unroll
    for (int mt = 0; mt < 4; ++mt) {
#pragma unroll
        for (int r = 0; r < 4; ++r) {
            const int o = wv * 64 + mt * 16 + (ln >> 4) * 4 + r;
            const float wbv = Wb[o];
            const float as = aw[o];
            const float ad = aw[256 + o];
#pragma unroll
            for (int nt = 0; nt < 2; ++nt) {
                const float v = acc[mt][nt][r] + wbv;
                psrc[nt] += v * as;
                pdst[nt] += v * ad;
                const int i = i0 + nt * 16 + (ln & 15);
                whT[(size_t)o * 8192 + i] = f2bf(v);
            }
        }
    }
#pragma unroll
    for (int off = 16; off < 64; off <<= 1) {
#pragma unroll
        for (int nt = 0; nt < 2; ++nt) {
            psrc[nt] += __shfl_xor(psrc[nt], off, 64);
            pdst[nt] += __shfl_xor(pdst[nt], off, 64);
        }
    }
    if (ln < 16) {
#pragma unroll
        for (int nt = 0; nt < 2; ++nt) {
            redLds[0][wv][nt * 16 + ln] = psrc[nt];
            redLds[1][wv][nt * 16 + ln] = pdst[nt];
        }
    }
    __syncthreads();
    if (t < 32) {
        float s = 0.f;
#pragma unroll
        for (int w = 0; w < 4; ++w) s += redLds[0][w][t];
        s_src[i0 + t] = s;
    } else if (t < 64) {
        float s = 0.f;
#pragma unroll
        for (int w = 0; w < 4; ++w) s += redLds[1][w][t - 32];
        s_dst[i0 + t - 32] = s;
    }
}

// ---------------------------------------------------------------------------
// K2: fused masked-softmax (no max-subtract, clamp 60 — formula validated r7)
//     + P @ wh via bf16 MFMA, f32 output. grid 256 x 512 thr (8 waves):
// dq=wv&3 owns 64 d's; kh=wv>>2 owns a 32-wide k-half of each 64-j tile;
// epilogue combines kh pairs via LDS, normalizes, writes f32.
// ---------------------------------------------------------------------------
__launch_bounds__(512, 2)
__global__ void k2_attn(const int* __restrict__ adj, const ushort_t* __restrict__ whT,
                        const float* __restrict__ s_src, const float* __restrict__ s_dst,
                        const float* __restrict__ ab_p, float* __restrict__ out) {
    __shared__ __align__(16) ushort_t wLds[256 * 72];  // whT tile [d][j]
    __shared__ __align__(16) ushort_t pLds[32 * 72];   // p tile [i][j]
    __shared__ float zLds[32];

    const int t = threadIdx.x;
    const int wv = t >> 6, ln = t & 63;
    const int dq = wv & 3, kh = wv >> 2;
    const int i0 = blockIdx.x * 32;
    const int prow = t >> 4, pjc = t & 15;  // p-compute: row 0..31, 4 j's each
    const int srow = t >> 3, sch = t & 7;   // staging: 64 rows/round, 8 lanes/row

    const float ab = ab_p[0];
    const float ssrc = s_src[i0 + prow];

    const int* aBase = adj + (size_t)(i0 + prow) * 8192 + pjc * 4;
    const float* sBase = s_dst + pjc * 4;
    const ushort_t* wBase = whT + (size_t)srow * 8192 + sch * 8;
    ushort_t* pDst = pLds + prow * 72 + pjc * 4;

    f32x4 acc[2][4];
#pragma unroll
    for (int mt = 0; mt < 2; ++mt)
#pragma unroll
        for (int nt = 0; nt < 4; ++nt) acc[mt][nt] = (f32x4){0.f, 0.f, 0.f, 0.f};
    float zacc = 0.f;

    // prefetch tile 0
    i32x4 Av = *(const i32x4*)aBase;
    f32x4 Sv = *(const f32x4*)sBase;
    u32x4 Wv[4];
#pragma unroll
    for (int r = 0; r < 4; ++r) Wv[r] = *(const u32x4*)(wBase + (size_t)r * 64 * 8192);

    for (int it = 0; it < 128; ++it) {
        const int jn = (it < 127) ? (it + 1) * 64 : it * 64;
        i32x4 Ac = Av;
        f32x4 Sc = Sv;
        u32x4 Wc[4];
#pragma unroll
        for (int r = 0; r < 4; ++r) Wc[r] = Wv[r];
        // issue next-tile loads; they land during this tile's LDS+MFMA phase
        Av = *(const i32x4*)(aBase + jn);
        Sv = *(const f32x4*)(sBase + jn);
#pragma unroll
        for (int r = 0; r < 4; ++r) Wv[r] = *(const u32x4*)(wBase + (size_t)r * 64 * 8192 + jn);

        __syncthreads();  // prev MFMA reads done -> LDS writable
#pragma unroll
        for (int r = 0; r < 4; ++r)
            *(u32x4*)(wLds + (r * 64 + srow) * 72 + sch * 8) = Wc[r];
        {
            u16x4 pv4;
            float z4 = 0.f;
#pragma unroll
            for (int k = 0; k < 4; ++k) {
                float sc = ssrc + Sc[k] + ab;
                sc = sc > 0.f ? sc : LRELU_SLOPE * sc;
                sc = fminf(sc, 60.f);
                float pv = (Ac[k] > 0) ? __expf(sc) : 0.f;
                z4 += pv;
                pv4[k] = f2bf(pv);
            }
            zacc += z4;
            *(u16x4*)pDst = pv4;
        }
        __syncthreads();
        {
            short8 b[4];
#pragma unroll
            for (int nt = 0; nt < 4; ++nt)
                b[nt] = *(const short8*)(wLds + (dq * 64 + nt * 16 + (ln & 15)) * 72 + kh * 32 + (ln >> 4) * 8);
#pragma unroll
            for (int mt = 0; mt < 2; ++mt) {
                short8 a = *(const short8*)(pLds + (mt * 16 + (ln & 15)) * 72 + kh * 32 + (ln >> 4) * 8);
#pragma unroll
                for (int nt = 0; nt < 4; ++nt)
                    acc[mt][nt] = __builtin_amdgcn_mfma_f32_16x16x32_bf16(a, b[nt], acc[mt][nt], 0, 0, 0);
            }
        }
    }

    // Z: sum the 16 threads of each row (aligned consecutive lanes)
    zacc += __shfl_xor(zacc, 1, 64);
    zacc += __shfl_xor(zacc, 2, 64);
    zacc += __shfl_xor(zacc, 4, 64);
    zacc += __shfl_xor(zacc, 8, 64);
    if ((t & 15) == 0) zLds[prow] = 1.0f / fmaxf(zacc, 1e-30f);

    __syncthreads();  // all MFMA LDS reads done; wLds reusable as exchange
    float* ex = (float*)wLds;  // stride 33 floats -> conflict-free
    if (kh == 1) {
        float* p = ex + (dq * 64 + ln) * 33;
#pragma unroll
        for (int mt = 0; mt < 2; ++mt)
#pragma unroll
            for (int nt = 0; nt < 4; ++nt)
#pragma unroll
                for (int r = 0; r < 4; ++r) p[mt * 16 + nt * 4 + r] = acc[mt][nt][r];
    }
    __syncthreads();
    if (kh == 0) {
        const float* p = ex + (dq * 64 + ln) * 33;
#pragma unroll
        for (int mt = 0; mt < 2; ++mt)
#pragma unroll
            for (int nt = 0; nt < 4; ++nt)
#pragma unroll
                for (int r = 0; r < 4; ++r) {
                    const int il = mt * 16 + (ln >> 4) * 4 + r;
                    const int d = dq * 64 + nt * 16 + (ln & 15);
                    out[(size_t)(i0 + il) * 256 + d] =
                        (acc[mt][nt][r] + p[mt * 16 + nt * 4 + r]) * zLds[il];
                }
    }
}

extern "C" void kernel_launch(void* const* d_in, const int* in_sizes, int n_in, void* d_out,
                              int out_size, void* d_ws, size_t ws_size, hipStream_t stream) {
    // identify inputs by flat size (validated r7): ab=1, Wb=256, aw=512,
    // Ww=131072, h=4194304, adj=67108864
    int order[16];
    for (int i = 0; i < n_in; ++i) order[i] = i;
    for (int a = 0; a < n_in; ++a)
        for (int b = a + 1; b < n_in; ++b)
            if (in_sizes[order[b]] < in_sizes[order[a]]) {
                int tmp = order[a]; order[a] = order[b]; order[b] = tmp;
            }
    const float* ab = (const float*)d_in[order[0]];
    const float* Wb = (const float*)d_in[order[1]];
    const float* aw = (const float*)d_in[order[2]];
    const float* Ww = (const float*)d_in[order[3]];
    const float* h = (const float*)d_in[order[4]];
    const int* adj = (const int*)d_in[order[5]];

    char* ws = (char*)d_ws;
    ushort_t* whT = (ushort_t*)ws;                 // 4 MB: 256 x 8192 bf16
    float* ssrc = (float*)(ws + 4194304);          // 32 KB
    float* sdst = (float*)(ws + 4194304 + 32768);  // 32 KB (total 4.26 MB)

    hipLaunchKernelGGL(k1_gemm, dim3(256), dim3(256), 0, stream, h, Ww, Wb, aw, whT, ssrc, sdst);
    hipLaunchKernelGGL(k2_attn, dim3(256), dim3(512), 0, stream, adj, whT, ssrc, sdst, ab,
                       (float*)d_out);
}